// Round 13
// baseline (238.731 us; speedup 1.0000x reference)
//
#include <hip/hip_runtime.h>

#define TT 512
#define BB 256
#define NN 128
#define MW 16            // chains per group
#define NWG (BB / MW)    // 16 chain-groups
#define STH 144          // state row stride in halves (288 B, 16B-aligned).
                         // R10 A/B: STH=136 raised bank conflicts 4.6x with
                         // zero timing delta -> conflicts hidden; 144 best.
#define GRID (32 + TT)   // 32 recursion + 512 score blocks

// ws layout (bytes)
#define LENS_OFF 256
#define AF_OFF 2048
#define CF_OFF (AF_OFF + BB * NN * 4)
#define BU_OFF (CF_OFF + 1024)
#define CB_OFF (BU_OFF + BB * NN * 4)
#define WS_NEED ((size_t)CB_OFF + 1024)

typedef __attribute__((ext_vector_type(8))) short short8_t;
typedef __attribute__((ext_vector_type(4))) float f32x4;

__device__ __forceinline__ unsigned short f2bf(float f) {
  unsigned u = __float_as_uint(f);
  return (unsigned short)((u + 0x7FFF + ((u >> 16) & 1)) >> 16);  // RNE
}
__device__ __forceinline__ float bf2f(unsigned short h) {
  return __uint_as_float(((unsigned)h) << 16);
}
// storage position p <-> original index:  idx = 32w+16u+c  <->  p = 32w+2c+u
__device__ __forceinline__ int orig_j(int p) {
  return 32 * (p >> 5) + 16 * (p & 1) + ((p >> 1) & 15);
}
// packed RNE f32->bf16 pair (lo=a, hi=b) — single VALU op
__device__ __forceinline__ unsigned pk_bf16(float a, float b) {
  unsigned r;
  asm("v_cvt_pk_bf16_f32 %0, %1, %2" : "=v"(r) : "v"(a), "v"(b));
  return r;
}

// lgkmcnt-only barrier: LDS producer/consumer ordering without draining
// outstanding global (emit prefetch) loads.
#define BARRIER_LGKM() \
  asm volatile("s_waitcnt lgkmcnt(0)\n\ts_barrier" ::: "memory")

// ---------- one recursion step (fb8 body + depth-1 MFMA split) -------------
// Contract: XU = x(T_) [consumed]; XF <- exp(RO) = x(T_ +/- 1) [produced,
// emitted right after the MFMA issue so it hides under MFMA latency];
// RL <- emit(T_ +/- 2) [global prefetch].
// R12 change: 8 independent MFMA accumulators (depth-1) + add tree, vs
// fb8's depth-2 chains — removes one dependent-MFMA latency from the
// critical path barrier->ds_read->MFMA->epilogue.
template <bool FWD>
__device__ __forceinline__ void step_one(
    int T_, bool NORM, const float* __restrict__ emit,
    unsigned short (&sVg)[2][MW * STH], int (&nrmg)[2][MW], int& nb,
    int (&cloc)[4], const int (&lm1)[4], const int (&off8)[8],
    float (&RL)[8], const float (&RO)[8], const float (&XU)[8],
    float (&XF)[8], const short8_t (&eB)[4][2], float eet0, float eet1,
    int w, int c, int qd, bool nwriter) {
  const int POUT = T_ & 1, PIN = POUT ^ 1;
  {
    int tl = FWD ? (T_ + 2 < TT ? T_ + 2 : TT - 1) : (T_ - 2 > 0 ? T_ - 2 : 0);
    const size_t gb = (size_t)tl * (BB * NN);
#pragma unroll
    for (int i = 0; i < 8; ++i) RL[i] = emit[gb + off8[i]];
  }
  const short8_t A0 = *(const short8_t*)&sVg[PIN][c * STH + 0 + qd * 8];
  const short8_t A1 = *(const short8_t*)&sVg[PIN][c * STH + 32 + qd * 8];
  const short8_t A2 = *(const short8_t*)&sVg[PIN][c * STH + 64 + qd * 8];
  const short8_t A3 = *(const short8_t*)&sVg[PIN][c * STH + 96 + qd * 8];
  const f32x4 z = {0.f, 0.f, 0.f, 0.f};
  f32x4 m00 = __builtin_amdgcn_mfma_f32_16x16x32_bf16(A0, eB[0][0], z, 0, 0, 0);
  f32x4 m01 = __builtin_amdgcn_mfma_f32_16x16x32_bf16(A0, eB[0][1], z, 0, 0, 0);
  f32x4 m10 = __builtin_amdgcn_mfma_f32_16x16x32_bf16(A1, eB[1][0], z, 0, 0, 0);
  f32x4 m11 = __builtin_amdgcn_mfma_f32_16x16x32_bf16(A1, eB[1][1], z, 0, 0, 0);
  f32x4 m20 = __builtin_amdgcn_mfma_f32_16x16x32_bf16(A2, eB[2][0], z, 0, 0, 0);
  f32x4 m21 = __builtin_amdgcn_mfma_f32_16x16x32_bf16(A2, eB[2][1], z, 0, 0, 0);
  f32x4 m30 = __builtin_amdgcn_mfma_f32_16x16x32_bf16(A3, eB[3][0], z, 0, 0, 0);
  f32x4 m31 = __builtin_amdgcn_mfma_f32_16x16x32_bf16(A3, eB[3][1], z, 0, 0, 0);
  // ---- hoisted exp for next step (independent of MFMA results) ----
#pragma unroll
  for (int i = 0; i < 8; ++i) XF[i] = __expf(RO[i]);
  const f32x4 ac0 = (m00 + m10) + (m20 + m30);
  const f32x4 ac1 = (m01 + m11) + (m21 + m31);

  if (NORM) {
    const int4 nr = *(const int4*)&nrmg[nb][4 * qd];
    const int nA[4] = {nr.x, nr.y, nr.z, nr.w};
    int nnw[4];
#pragma unroll
    for (int r_ = 0; r_ < 4; ++r_) {
      float v0, v1;
      if (FWD) {
        v0 = ldexpf(ac0[r_] * XU[2 * r_], -nA[r_]);
        v1 = ldexpf(ac1[r_] * XU[2 * r_ + 1], -nA[r_]);
        if (T_ <= lm1[r_]) {
          *(unsigned*)&sVg[POUT][(4 * qd + r_) * STH + 32 * w + 2 * c] =
              pk_bf16(v0, v1);
          cloc[r_] += nA[r_];
        }
      } else {
        const bool isact = (T_ == lm1[r_]);
        v0 = isact ? XU[2 * r_] * eet0 : ldexpf(ac0[r_] * XU[2 * r_], -nA[r_]);
        v1 = isact ? XU[2 * r_ + 1] * eet1
                   : ldexpf(ac1[r_] * XU[2 * r_ + 1], -nA[r_]);
        if (T_ <= lm1[r_]) {
          *(unsigned*)&sVg[POUT][(4 * qd + r_) * STH + 32 * w + 2 * c] =
              pk_bf16(v0, v1);
          cloc[r_] = isact ? 0 : cloc[r_] + nA[r_];
        }
      }
      nnw[r_] = ((int)((__float_as_uint(v0) >> 23) & 0xFF)) - 120;
    }
    if (nwriter)
      *(int4*)&nrmg[nb ^ 1][4 * qd] = make_int4(nnw[0], nnw[1], nnw[2], nnw[3]);
    nb ^= 1;
  } else {
#pragma unroll
    for (int r_ = 0; r_ < 4; ++r_) {
      float v0, v1;
      if (FWD) {
        v0 = ac0[r_] * XU[2 * r_];
        v1 = ac1[r_] * XU[2 * r_ + 1];
        if (T_ <= lm1[r_]) {
          *(unsigned*)&sVg[POUT][(4 * qd + r_) * STH + 32 * w + 2 * c] =
              pk_bf16(v0, v1);
        }
      } else {
        const bool isact = (T_ == lm1[r_]);
        v0 = isact ? XU[2 * r_] * eet0 : ac0[r_] * XU[2 * r_];
        v1 = isact ? XU[2 * r_ + 1] * eet1 : ac1[r_] * XU[2 * r_ + 1];
        if (T_ <= lm1[r_]) {
          *(unsigned*)&sVg[POUT][(4 * qd + r_) * STH + 32 * w + 2 * c] =
              pk_bf16(v0, v1);
          cloc[r_] = isact ? 0 : cloc[r_];
        }
      }
    }
  }
}

// ---------- Phase 1: recursions (blocks 0..31) + in-grid score -------------
// Blocks 0..15: fwd group bid;  16..31: bwd group bid-16.
// Blocks 32..543: gold-score.  Step body: fb8 (exp-hoist + x dbuf),
// norm cadence 4, STH=144, depth-1 MFMA split.
__global__ __launch_bounds__(256, 1) void crf_fb12(
    const float* __restrict__ emit, const int* __restrict__ target,
    const void* __restrict__ maskp, const float* __restrict__ trans,
    const float* __restrict__ strans, const float* __restrict__ etrans,
    float* __restrict__ ws, int* __restrict__ lens, float* __restrict__ AF,
    int* __restrict__ CF, float* __restrict__ BU, int* __restrict__ CB) {
  __shared__ __align__(16) unsigned short sV[2][MW * STH];
  __shared__ __align__(16) int nrm[2][MW];
  __shared__ __align__(16) int sC[MW];
  __shared__ int slen[MW];
  __shared__ int smax_s;
  __shared__ float rf[4];

  const int bid = blockIdx.x;
  const int tid = threadIdx.x;
  const unsigned char* mk8 = (const unsigned char*)maskp;
  const int* mk32 = (const int*)maskp;
  const bool is_u8 = (mk8[1] != 0);

  if (bid >= 32) {
    // ---------------- gold score (one t per block) ----------------
    const int b = tid;
    const int t = bid - 32;
    int m = is_u8 ? (mk8[t * BB + b] != 0) : (mk32[t * BB + b] != 0);
    float v = 0.f;
    if (m) {
      int tg = target[t * BB + b];
      v = emit[((size_t)t * BB + b) * NN + tg];
      v += (t > 0) ? trans[target[(t - 1) * BB + b] * NN + tg] : strans[tg];
      int mn = (t + 1 < TT) ? (is_u8 ? (mk8[(t + 1) * BB + b] != 0)
                                     : (mk32[(t + 1) * BB + b] != 0))
                            : 0;
      if (!mn) {  // prefix-mask edge = last valid step
        v += etrans[tg];
        lens[b] = t + 1;
      }
    }
#pragma unroll
    for (int off = 32; off; off >>= 1) v += __shfl_down(v, off, 64);
    if ((b & 63) == 0) rf[b >> 6] = v;
    __syncthreads();
    if (b == 0) atomicAdd(&ws[1], rf[0] + rf[1] + rf[2] + rf[3]);
    return;
  }

  // ---------------- recursion block (one group) ----------------
  const bool bwd = (bid >= NWG);
  const int g = bwd ? bid - NWG : bid;
  const int bg = g * MW;
  const int w = tid >> 6, l = tid & 63, c = l & 15, qd = l >> 4;

  if (tid == 0) smax_s = 0;
  __syncthreads();
  // per-chain length via binary search on the prefix-true mask
  if (tid < MW) {
    const int b = bg + tid;
    int len = 1;
#pragma unroll
    for (int st = 256; st; st >>= 1) {
      int t2 = len + st;
      if (t2 <= TT) {
        bool mv = is_u8 ? (mk8[(size_t)(t2 - 1) * BB + b] != 0)
                        : (mk32[(size_t)(t2 - 1) * BB + b] != 0);
        if (mv) len = t2;
      }
    }
    slen[tid] = len;
    atomicMax(&smax_s, len);
  }

  // ---- E fragments (bwd: transposed orientation) ----
  short8_t eB[4][2];
#pragma unroll
  for (int kt = 0; kt < 4; ++kt)
#pragma unroll
    for (int u = 0; u < 2; ++u)
#pragma unroll
      for (int jj = 0; jj < 8; ++jj) {
        int kp = kt * 32 + qd * 8 + jj;
        int a_ = orig_j(kp);
        int b_ = 32 * w + 16 * u + c;
        float tv = bwd ? trans[b_ * NN + a_] : trans[a_ * NN + b_];
        eB[kt][u][jj] = (short)f2bf(__expf(tv));
      }
  const float eet0 = __expf(etrans[32 * w + c]);
  const float eet1 = __expf(etrans[32 * w + 16 + c]);

  // ---- init state ----
  {
    const int m = tid & 15;
    const int pbase = (tid >> 4) * 8;
    if (!bwd) {
      const int b = bg + m;
#pragma unroll
      for (int pp = 0; pp < 8; ++pp) {
        int p = pbase + pp;
        int j = orig_j(p);
        float v = __expf(strans[j] + emit[(size_t)b * NN + j]);
        sV[0][m * STH + p] = f2bf(v);
        if (p == 0)
          nrm[0][m] = ((int)((__float_as_uint(v) >> 23) & 0xFF)) - 120;
      }
    } else {
#pragma unroll
      for (int pp = 0; pp < 8; ++pp) {
        int p = pbase + pp;
        sV[0][m * STH + p] = 0x3F80;  // 1.0 bf16
        sV[1][m * STH + p] = 0x3F80;
        if (p == 0) { nrm[0][m] = 0; nrm[1][m] = 0; }
      }
    }
  }
  __syncthreads();
  const int smax = smax_s;
  int lm1[4];
#pragma unroll
  for (int r = 0; r < 4; ++r) lm1[r] = slen[4 * qd + r] - 1;

  int cloc[4] = {0, 0, 0, 0};
  int nb = 0;
  const bool nwriter = (w == 0 && c == 0);

  int off8[8];
#pragma unroll
  for (int r = 0; r < 4; ++r)
#pragma unroll
    for (int u = 0; u < 2; ++u)
      off8[r * 2 + u] = (bg + 4 * qd + r) * NN + 32 * w + 16 * u + c;

  int NIT, T0;
  if (!bwd) {
    const int LmaxF = (smax < 258) ? smax : 258;
    NIT = LmaxF - 1;  // steps T = 1..LmaxF-1 (T = T0 + it)
    T0 = 1;
  } else {
    NIT = (smax >= 259) ? smax - 258 : 0;  // steps T = smax-1..258 (T0 - it)
    T0 = smax - 1;
  }

  if (NIT > 0) {
    // prefetch init: ra = emit[T0], rb = emit[T0 +/- 1], x0 = exp(ra)
    float ra[8], rb[8], x0[8], x1[8];
    {
      const int a1 = bwd ? (T0 - 1 > 0 ? T0 - 1 : 0)
                         : (T0 + 1 < TT ? T0 + 1 : TT - 1);
#pragma unroll
      for (int i = 0; i < 8; ++i) {
        ra[i] = emit[(size_t)T0 * (BB * NN) + off8[i]];
        rb[i] = emit[(size_t)a1 * (BB * NN) + off8[i]];
      }
#pragma unroll
      for (int i = 0; i < 8; ++i) x0[i] = __expf(ra[i]);
    }
    // norm cadence 4 (exact 2^n bookkeeping; growth over 4 steps << f32 max)
    if (!bwd) {
      for (int itb = 0; itb < NIT; itb += 4) {
#pragma unroll
        for (int k = 0; k < 4; ++k) {
          const int it = itb + k;
          if (it >= NIT) break;  // NIT block-uniform: barrier-safe
          if ((k & 1) == 0)
            step_one<true>(T0 + it, k == 3, emit, sV, nrm, nb, cloc, lm1, off8,
                           ra, rb, x0, x1, eB, eet0, eet1, w, c, qd, nwriter);
          else
            step_one<true>(T0 + it, k == 3, emit, sV, nrm, nb, cloc, lm1, off8,
                           rb, ra, x1, x0, eB, eet0, eet1, w, c, qd, nwriter);
          BARRIER_LGKM();
        }
      }
    } else {
      for (int itb = 0; itb < NIT; itb += 4) {
#pragma unroll
        for (int k = 0; k < 4; ++k) {
          const int it = itb + k;
          if (it >= NIT) break;
          if ((k & 1) == 0)
            step_one<false>(T0 - it, k == 3, emit, sV, nrm, nb, cloc, lm1,
                            off8, ra, rb, x0, x1, eB, eet0, eet1, w, c, qd,
                            nwriter);
          else
            step_one<false>(T0 - it, k == 3, emit, sV, nrm, nb, cloc, lm1,
                            off8, rb, ra, x1, x0, eB, eet0, eet1, w, c, qd,
                            nwriter);
          BARRIER_LGKM();
        }
      }
    }
  }

  // ---- epilogue: dump per-chain state + pow2 counters to global ----
  if (nwriter)
    *(int4*)&sC[4 * qd] = make_int4(cloc[0], cloc[1], cloc[2], cloc[3]);
  __syncthreads();
  {
    const int m = tid >> 4, i16 = tid & 15;
    if (!bwd) {
      int nf = slen[m] - 1;
      if (nf > 257) nf = 257;
      const int pf = nf & 1;
#pragma unroll
      for (int pp = 0; pp < 8; ++pp) {
        int p = i16 * 8 + pp;
        AF[(size_t)(bg + m) * NN + p] = bf2f(sV[pf][m * STH + p]);
      }
      if (i16 == 0) CF[bg + m] = sC[m];
    } else {
      // active chains all end at t=258 -> parity 0; inactive: init (unused)
#pragma unroll
      for (int pp = 0; pp < 8; ++pp) {
        int p = i16 * 8 + pp;
        BU[(size_t)(bg + m) * NN + p] = bf2f(sV[0][m * STH + p]);
      }
      if (i16 == 0) CB[bg + m] = sC[m];
    }
  }
}

// ---------- Phase 2: combine.  logZ_b = ln2*(CF+CB) + ln(alpha_257 . E U_258)
// (len>=259) or ln2*CF + ln(alpha . exp(etrans)) (len<=258). ----------------
__global__ __launch_bounds__(256) void crf_comb(
    const float* __restrict__ trans, const float* __restrict__ etrans,
    const int* __restrict__ lens, const float* __restrict__ AF,
    const int* __restrict__ CF, const float* __restrict__ BU,
    const int* __restrict__ CB, float* __restrict__ ws,
    float* __restrict__ out) {
  __shared__ __align__(16) unsigned short sU[MW * STH];
  __shared__ float sRed[4][MW][2];
  __shared__ int slen[MW];
  const int tid = threadIdx.x;
  const int w = tid >> 6, l = tid & 63, c = l & 15, qd = l >> 4;
  const int g = blockIdx.x, bg = g * MW;

  if (tid < MW) slen[tid] = lens[bg + tid];
  {
    const int m = tid & 15, pbase = (tid >> 4) * 8;
#pragma unroll
    for (int pp = 0; pp < 8; ++pp) {
      int p = pbase + pp;
      sU[m * STH + p] = f2bf(BU[(size_t)(bg + m) * NN + p]);
    }
  }
  short8_t eB[4][2];
#pragma unroll
  for (int kt = 0; kt < 4; ++kt)
#pragma unroll
    for (int u = 0; u < 2; ++u)
#pragma unroll
      for (int jj = 0; jj < 8; ++jj) {
        int kp = kt * 32 + qd * 8 + jj;
        int a_ = orig_j(kp);
        int b_ = 32 * w + 16 * u + c;
        eB[kt][u][jj] = (short)f2bf(__expf(trans[b_ * NN + a_]));  // bwd orient
      }
  const float eet0 = __expf(etrans[32 * w + c]);
  const float eet1 = __expf(etrans[32 * w + 16 + c]);
  __syncthreads();

  const short8_t A0 = *(const short8_t*)&sU[c * STH + 0 + qd * 8];
  const short8_t A1 = *(const short8_t*)&sU[c * STH + 32 + qd * 8];
  const short8_t A2 = *(const short8_t*)&sU[c * STH + 64 + qd * 8];
  const short8_t A3 = *(const short8_t*)&sU[c * STH + 96 + qd * 8];
  f32x4 ac0 = {0.f, 0.f, 0.f, 0.f}, ac1 = {0.f, 0.f, 0.f, 0.f};
  ac0 = __builtin_amdgcn_mfma_f32_16x16x32_bf16(A0, eB[0][0], ac0, 0, 0, 0);
  ac1 = __builtin_amdgcn_mfma_f32_16x16x32_bf16(A0, eB[0][1], ac1, 0, 0, 0);
  ac0 = __builtin_amdgcn_mfma_f32_16x16x32_bf16(A1, eB[1][0], ac0, 0, 0, 0);
  ac1 = __builtin_amdgcn_mfma_f32_16x16x32_bf16(A1, eB[1][1], ac1, 0, 0, 0);
  ac0 = __builtin_amdgcn_mfma_f32_16x16x32_bf16(A2, eB[2][0], ac0, 0, 0, 0);
  ac1 = __builtin_amdgcn_mfma_f32_16x16x32_bf16(A2, eB[2][1], ac1, 0, 0, 0);
  ac0 = __builtin_amdgcn_mfma_f32_16x16x32_bf16(A3, eB[3][0], ac0, 0, 0, 0);
  ac1 = __builtin_amdgcn_mfma_f32_16x16x32_bf16(A3, eB[3][1], ac1, 0, 0, 0);

#pragma unroll
  for (int r_ = 0; r_ < 4; ++r_) {
    // alpha at cols i0 = 32w+c (p=32w+2c), i1 = 32w+16+c (p=32w+2c+1)
    float a0 = AF[(size_t)(bg + 4 * qd + r_) * NN + 32 * w + 2 * c];
    float a1 = AF[(size_t)(bg + 4 * qd + r_) * NN + 32 * w + 2 * c + 1];
    float dB = a0 * ac0[r_] + a1 * ac1[r_];
    float dA = a0 * eet0 + a1 * eet1;
#pragma unroll
    for (int mk = 1; mk < 16; mk <<= 1) {
      dB += __shfl_xor(dB, mk, 64);
      dA += __shfl_xor(dA, mk, 64);
    }
    if (c == 0) {
      sRed[w][4 * qd + r_][0] = dB;
      sRed[w][4 * qd + r_][1] = dA;
    }
  }
  __syncthreads();
  if (tid < MW) {
    float DB = sRed[0][tid][0] + sRed[1][tid][0] + sRed[2][tid][0] + sRed[3][tid][0];
    float DA = sRed[0][tid][1] + sRed[1][tid][1] + sRed[2][tid][1] + sRed[3][tid][1];
    const int len = slen[tid];
    const float LN2 = 0.6931471805599453f;
    float logZ;
    if (len >= 259)
      logZ = LN2 * (float)(CF[bg + tid] + CB[bg + tid]) + __logf(DB);
    else
      logZ = LN2 * (float)CF[bg + tid] + __logf(DA);
    atomicAdd(&ws[0], logZ);
  }
  __syncthreads();
  if (tid == 0) {
    __threadfence();
    unsigned old = atomicAdd((unsigned*)ws + 3, 1u);
    if (old == NWG - 1) {
      float zz = atomicAdd(&ws[0], 0.f);
      float ss = atomicAdd(&ws[1], 0.f);
      out[0] = (zz - ss) * (1.0f / (float)BB);
    }
  }
}

// ---------- Fallback (Round-5 fused kernel, verified) ----------------------
__global__ __launch_bounds__(256, 1) void crf_fused_fb(
    const float* __restrict__ emit, const int* __restrict__ target,
    const void* __restrict__ maskp, const float* __restrict__ trans,
    const float* __restrict__ strans, const float* __restrict__ etrans,
    float* __restrict__ ws, float* __restrict__ out) {
  __shared__ __align__(16) unsigned short sV[2][MW * STH];
  __shared__ __align__(16) int nrm[2][MW];
  __shared__ __align__(16) int sC[MW];
  __shared__ int slen[MW];
  __shared__ float sscore;
  __shared__ int smax;

  const int tid = threadIdx.x;
  const int w = tid >> 6;
  const int l = tid & 63;
  const int c = l & 15;
  const int qd = l >> 4;
  const int bg = blockIdx.x * MW;

  if (tid < MW) slen[tid] = 0;
  if (tid == 0) { sscore = 0.f; smax = 0; }
  __syncthreads();

  const unsigned char* mk8 = (const unsigned char*)maskp;
  const int* mk32 = (const int*)maskp;
  const bool is_u8 = (mk8[1] != 0);
  {
    const int mi = tid & 15;
    const int b = bg + mi;
    const int t0 = (tid >> 4) * 32;
    int cnt = 0;
    float sc = 0.f;
    for (int s = 0; s < 32; ++s) {
      int t = t0 + s;
      int m = is_u8 ? (mk8[t * BB + b] != 0) : (mk32[t * BB + b] != 0);
      if (m) {
        cnt++;
        int tg = target[t * BB + b];
        float v = emit[((size_t)t * BB + b) * NN + tg];
        v += (t > 0) ? trans[target[(t - 1) * BB + b] * NN + tg] : strans[tg];
        int mn = (t + 1 < TT) ? (is_u8 ? (mk8[(t + 1) * BB + b] != 0)
                                       : (mk32[(t + 1) * BB + b] != 0))
                              : 0;
        if (!mn) v += etrans[tg];
        sc += v;
      }
    }
    atomicAdd(&slen[mi], cnt);
    atomicAdd(&sscore, sc);
  }

  short8_t eB[4][2];
#pragma unroll
  for (int kt = 0; kt < 4; ++kt)
#pragma unroll
    for (int u = 0; u < 2; ++u)
#pragma unroll
      for (int jj = 0; jj < 8; ++jj) {
        int kp = kt * 32 + qd * 8 + jj;
        int i = orig_j(kp);
        int j = 32 * w + 16 * u + c;
        eB[kt][u][jj] = (short)f2bf(__expf(trans[i * NN + j]));
      }

  {
    const int m = tid & 15;
    const int b = bg + m;
    const int pbase = (tid >> 4) * 8;
#pragma unroll
    for (int pp = 0; pp < 8; ++pp) {
      int p = pbase + pp;
      int j = orig_j(p);
      float v = __expf(strans[j] + emit[(size_t)b * NN + j]);
      sV[0][m * STH + p] = f2bf(v);
      if (p == 0)
        nrm[0][m] = ((int)((__float_as_uint(v) >> 23) & 0xFF)) - 120;
    }
  }
  __syncthreads();

  if (tid < MW) atomicMax(&smax, slen[tid]);
  if (tid == 0) atomicAdd(&ws[1], sscore);
  __syncthreads();
  const int Lmax = smax;
  int lenr[4];
#pragma unroll
  for (int r = 0; r < 4; ++r) lenr[r] = slen[4 * qd + r];

  int off8[8];
#pragma unroll
  for (int r = 0; r < 4; ++r)
#pragma unroll
    for (int u = 0; u < 2; ++u)
      off8[r * 2 + u] = (bg + 4 * qd + r) * NN + 32 * w + 16 * u + c;

  float ra[8], rb[8], xv[8];
  {
#pragma unroll
    for (int i = 0; i < 8; ++i) ra[i] = emit[(size_t)1 * BB * NN + off8[i]];
#pragma unroll
    for (int i = 0; i < 8; ++i) rb[i] = emit[(size_t)2 * BB * NN + off8[i]];
#pragma unroll
    for (int i = 0; i < 8; ++i) xv[i] = __expf(ra[i]);
  }
  int cloc[4] = {0, 0, 0, 0};
  const bool nwriter = (w == 0 && c == 0);

#define CRF_STEP(T_, PIN, POUT, RL, RO)                                       \
  do {                                                                        \
    int tl = ((T_) + 2 < TT) ? (T_) + 2 : TT - 1;                             \
    const size_t gbase = (size_t)tl * (BB * NN);                              \
    _Pragma("unroll") for (int i_ = 0; i_ < 8; ++i_)                          \
        RL[i_] = emit[gbase + off8[i_]];                                      \
    const short8_t A0 = *(const short8_t*)&sV[PIN][c * STH + 0 + qd * 8];     \
    const short8_t A1 = *(const short8_t*)&sV[PIN][c * STH + 32 + qd * 8];    \
    const short8_t A2 = *(const short8_t*)&sV[PIN][c * STH + 64 + qd * 8];    \
    const short8_t A3 = *(const short8_t*)&sV[PIN][c * STH + 96 + qd * 8];    \
    const int4 nr = *(const int4*)&nrm[PIN][4 * qd];                          \
    f32x4 ac0 = {0.f, 0.f, 0.f, 0.f}, ac1 = {0.f, 0.f, 0.f, 0.f};             \
    ac0 = __builtin_amdgcn_mfma_f32_16x16x32_bf16(A0, eB[0][0], ac0, 0, 0, 0);\
    ac1 = __builtin_amdgcn_mfma_f32_16x16x32_bf16(A0, eB[0][1], ac1, 0, 0, 0);\
    ac0 = __builtin_amdgcn_mfma_f32_16x16x32_bf16(A1, eB[1][0], ac0, 0, 0, 0);\
    ac1 = __builtin_amdgcn_mfma_f32_16x16x32_bf16(A1, eB[1][1], ac1, 0, 0, 0);\
    ac0 = __builtin_amdgcn_mfma_f32_16x16x32_bf16(A2, eB[2][0], ac0, 0, 0, 0);\
    ac1 = __builtin_amdgcn_mfma_f32_16x16x32_bf16(A2, eB[2][1], ac1, 0, 0, 0);\
    ac0 = __builtin_amdgcn_mfma_f32_16x16x32_bf16(A3, eB[3][0], ac0, 0, 0, 0);\
    ac1 = __builtin_amdgcn_mfma_f32_16x16x32_bf16(A3, eB[3][1], ac1, 0, 0, 0);\
    const int nA[4] = {nr.x, nr.y, nr.z, nr.w};                               \
    int nnw[4];                                                               \
    _Pragma("unroll") for (int r_ = 0; r_ < 4; ++r_) {                        \
      float y0 = ac0[r_] * xv[2 * r_];                                        \
      float y1 = ac1[r_] * xv[2 * r_ + 1];                                    \
      float v0 = ldexpf(y0, -nA[r_]);                                         \
      float v1 = ldexpf(y1, -nA[r_]);                                         \
      if ((T_) < lenr[r_]) {                                                  \
        unsigned pk = (unsigned)f2bf(v0) | ((unsigned)f2bf(v1) << 16);        \
        *(unsigned*)&sV[POUT][(4 * qd + r_) * STH + 32 * w + 2 * c] = pk;     \
        cloc[r_] += nA[r_];                                                   \
      }                                                                       \
      nnw[r_] = ((int)((__float_as_uint(v0) >> 23) & 0xFF)) - 120;            \
    }                                                                         \
    if (nwriter)                                                              \
      *(int4*)&nrm[POUT][4 * qd] = make_int4(nnw[0], nnw[1], nnw[2], nnw[3]); \
    _Pragma("unroll") for (int i_ = 0; i_ < 8; ++i_)                          \
        xv[i_] = __expf(RO[i_]);                                              \
    __syncthreads();                                                          \
  } while (0)

  for (int t = 1; t < Lmax; t += 2) {
    CRF_STEP(t, 0, 1, ra, rb);
    if (t + 1 < Lmax) {
      CRF_STEP(t + 1, 1, 0, rb, ra);
    }
  }
#undef CRF_STEP

  if (nwriter) *(int4*)&sC[4 * qd] = make_int4(cloc[0], cloc[1], cloc[2], cloc[3]);
  __syncthreads();
  {
    const int m = tid >> 4, i16 = tid & 15;
    const int pb = (slen[m] - 1) & 1;
    float s = 0.f;
#pragma unroll
    for (int pp = 0; pp < 8; ++pp) {
      int p = i16 * 8 + pp;
      int j = orig_j(p);
      s += bf2f(sV[pb][m * STH + p]) * __expf(etrans[j]);
    }
    s += __shfl_xor(s, 1, 64);
    s += __shfl_xor(s, 2, 64);
    s += __shfl_xor(s, 4, 64);
    s += __shfl_xor(s, 8, 64);
    if (i16 == 0)
      atomicAdd(&ws[0], (float)sC[m] * 0.69314718f + __logf(s));
  }
  __syncthreads();
  if (tid == 0) {
    __threadfence();
    unsigned old = atomicAdd((unsigned*)ws + 3, 1u);
    if (old == NWG - 1) {
      float zz = atomicAdd(&ws[0], 0.f);
      float ss = atomicAdd(&ws[1], 0.f);
      out[0] = (zz - ss) * (1.0f / (float)BB);
    }
  }
}

extern "C" void kernel_launch(void* const* d_in, const int* in_sizes, int n_in,
                              void* d_out, int out_size, void* d_ws, size_t ws_size,
                              hipStream_t stream) {
  const float* emit = (const float*)d_in[0];
  const int* target = (const int*)d_in[1];
  const void* mask = (const void*)d_in[2];
  const float* trans = (const float*)d_in[3];
  const float* strans = (const float*)d_in[4];
  const float* etrans = (const float*)d_in[5];
  float* ws = (float*)d_ws;
  float* out = (float*)d_out;

  hipMemsetAsync(d_ws, 0, 16, stream);
  if (ws_size >= WS_NEED) {
    int* lens = (int*)((char*)d_ws + LENS_OFF);
    float* AF = (float*)((char*)d_ws + AF_OFF);
    int* CF = (int*)((char*)d_ws + CF_OFF);
    float* BU = (float*)((char*)d_ws + BU_OFF);
    int* CB = (int*)((char*)d_ws + CB_OFF);
    crf_fb12<<<GRID, 256, 0, stream>>>(emit, target, mask, trans, strans,
                                       etrans, ws, lens, AF, CF, BU, CB);
    crf_comb<<<NWG, 256, 0, stream>>>(trans, etrans, lens, AF, CF, BU, CB, ws,
                                      out);
  } else {
    crf_fused_fb<<<NWG, 256, 0, stream>>>(emit, target, mask, trans, strans,
                                          etrans, ws, out);
  }
}

// Round 14
// 228.158 us; speedup vs baseline: 1.0463x; 1.0463x over previous
//
#include <hip/hip_runtime.h>

#define TT 512
#define BB 256
#define NN 128
#define MW 16            // chains per group
#define NWG (BB / MW)    // 16 chain-groups
#define STH 144          // state row stride in halves (288 B, 16B-aligned).
                         // R10 A/B: STH=136 raised bank conflicts 4.6x with
                         // zero timing delta -> conflicts hidden; 144 best.
#define GRID (32 + TT)   // 32 recursion + 512 score blocks

// ws layout (bytes)
#define LENS_OFF 256
#define AF_OFF 2048
#define CF_OFF (AF_OFF + BB * NN * 4)
#define BU_OFF (CF_OFF + 1024)
#define CB_OFF (BU_OFF + BB * NN * 4)
#define WS_NEED ((size_t)CB_OFF + 1024)

typedef __attribute__((ext_vector_type(8))) short short8_t;
typedef __attribute__((ext_vector_type(4))) float f32x4;

__device__ __forceinline__ unsigned short f2bf(float f) {
  unsigned u = __float_as_uint(f);
  return (unsigned short)((u + 0x7FFF + ((u >> 16) & 1)) >> 16);  // RNE
}
__device__ __forceinline__ float bf2f(unsigned short h) {
  return __uint_as_float(((unsigned)h) << 16);
}
// storage position p <-> original index:  idx = 32w+16u+c  <->  p = 32w+2c+u
__device__ __forceinline__ int orig_j(int p) {
  return 32 * (p >> 5) + 16 * (p & 1) + ((p >> 1) & 15);
}
// packed RNE f32->bf16 pair (lo=a, hi=b) — single VALU op
__device__ __forceinline__ unsigned pk_bf16(float a, float b) {
  unsigned r;
  asm("v_cvt_pk_bf16_f32 %0, %1, %2" : "=v"(r) : "v"(a), "v"(b));
  return r;
}

// lgkmcnt-only barrier: LDS producer/consumer ordering without draining
// outstanding global (emit prefetch) loads.
#define BARRIER_LGKM() \
  asm volatile("s_waitcnt lgkmcnt(0)\n\ts_barrier" ::: "memory")

// ---------- one recursion step (fb8/fb11 body — measured best) -------------
// Contract: XU = x(T_) [consumed]; XF <- exp(RO) = x(T_ +/- 1) [produced,
// emitted right after the MFMA issue so it hides under MFMA latency];
// RL <- emit(T_ +/- 2) [global prefetch].
// R13 note: depth-2 MFMA chains (accumulate via C-operand) are measured
// FASTER than a depth-1 split + add tree (fb12: +5-7 us, VALUBusy 3.1->3.8)
// — MFMA accumulation is free in-pipe; add trees expose VALU latency.
template <bool FWD>
__device__ __forceinline__ void step_one(
    int T_, bool NORM, const float* __restrict__ emit,
    unsigned short (&sVg)[2][MW * STH], int (&nrmg)[2][MW], int& nb,
    int (&cloc)[4], const int (&lm1)[4], const int (&off8)[8],
    float (&RL)[8], const float (&RO)[8], const float (&XU)[8],
    float (&XF)[8], const short8_t (&eB)[4][2], float eet0, float eet1,
    int w, int c, int qd, bool nwriter) {
  const int POUT = T_ & 1, PIN = POUT ^ 1;
  {
    int tl = FWD ? (T_ + 2 < TT ? T_ + 2 : TT - 1) : (T_ - 2 > 0 ? T_ - 2 : 0);
    const size_t gb = (size_t)tl * (BB * NN);
#pragma unroll
    for (int i = 0; i < 8; ++i) RL[i] = emit[gb + off8[i]];
  }
  const short8_t A0 = *(const short8_t*)&sVg[PIN][c * STH + 0 + qd * 8];
  const short8_t A1 = *(const short8_t*)&sVg[PIN][c * STH + 32 + qd * 8];
  const short8_t A2 = *(const short8_t*)&sVg[PIN][c * STH + 64 + qd * 8];
  const short8_t A3 = *(const short8_t*)&sVg[PIN][c * STH + 96 + qd * 8];
  f32x4 p0 = {0.f, 0.f, 0.f, 0.f}, q0 = {0.f, 0.f, 0.f, 0.f};
  f32x4 p1 = {0.f, 0.f, 0.f, 0.f}, q1 = {0.f, 0.f, 0.f, 0.f};
  p0 = __builtin_amdgcn_mfma_f32_16x16x32_bf16(A0, eB[0][0], p0, 0, 0, 0);
  p1 = __builtin_amdgcn_mfma_f32_16x16x32_bf16(A0, eB[0][1], p1, 0, 0, 0);
  q0 = __builtin_amdgcn_mfma_f32_16x16x32_bf16(A2, eB[2][0], q0, 0, 0, 0);
  q1 = __builtin_amdgcn_mfma_f32_16x16x32_bf16(A2, eB[2][1], q1, 0, 0, 0);
  p0 = __builtin_amdgcn_mfma_f32_16x16x32_bf16(A1, eB[1][0], p0, 0, 0, 0);
  p1 = __builtin_amdgcn_mfma_f32_16x16x32_bf16(A1, eB[1][1], p1, 0, 0, 0);
  q0 = __builtin_amdgcn_mfma_f32_16x16x32_bf16(A3, eB[3][0], q0, 0, 0, 0);
  q1 = __builtin_amdgcn_mfma_f32_16x16x32_bf16(A3, eB[3][1], q1, 0, 0, 0);
  // ---- hoisted exp for next step (independent of MFMA results) ----
#pragma unroll
  for (int i = 0; i < 8; ++i) XF[i] = __expf(RO[i]);
  const f32x4 ac0 = p0 + q0;
  const f32x4 ac1 = p1 + q1;

  if (NORM) {
    const int4 nr = *(const int4*)&nrmg[nb][4 * qd];
    const int nA[4] = {nr.x, nr.y, nr.z, nr.w};
    int nnw[4];
#pragma unroll
    for (int r_ = 0; r_ < 4; ++r_) {
      float v0, v1;
      if (FWD) {
        v0 = ldexpf(ac0[r_] * XU[2 * r_], -nA[r_]);
        v1 = ldexpf(ac1[r_] * XU[2 * r_ + 1], -nA[r_]);
        if (T_ <= lm1[r_]) {
          *(unsigned*)&sVg[POUT][(4 * qd + r_) * STH + 32 * w + 2 * c] =
              pk_bf16(v0, v1);
          cloc[r_] += nA[r_];
        }
      } else {
        const bool isact = (T_ == lm1[r_]);
        v0 = isact ? XU[2 * r_] * eet0 : ldexpf(ac0[r_] * XU[2 * r_], -nA[r_]);
        v1 = isact ? XU[2 * r_ + 1] * eet1
                   : ldexpf(ac1[r_] * XU[2 * r_ + 1], -nA[r_]);
        if (T_ <= lm1[r_]) {
          *(unsigned*)&sVg[POUT][(4 * qd + r_) * STH + 32 * w + 2 * c] =
              pk_bf16(v0, v1);
          cloc[r_] = isact ? 0 : cloc[r_] + nA[r_];
        }
      }
      nnw[r_] = ((int)((__float_as_uint(v0) >> 23) & 0xFF)) - 120;
    }
    if (nwriter)
      *(int4*)&nrmg[nb ^ 1][4 * qd] = make_int4(nnw[0], nnw[1], nnw[2], nnw[3]);
    nb ^= 1;
  } else {
#pragma unroll
    for (int r_ = 0; r_ < 4; ++r_) {
      float v0, v1;
      if (FWD) {
        v0 = ac0[r_] * XU[2 * r_];
        v1 = ac1[r_] * XU[2 * r_ + 1];
        if (T_ <= lm1[r_]) {
          *(unsigned*)&sVg[POUT][(4 * qd + r_) * STH + 32 * w + 2 * c] =
              pk_bf16(v0, v1);
        }
      } else {
        const bool isact = (T_ == lm1[r_]);
        v0 = isact ? XU[2 * r_] * eet0 : ac0[r_] * XU[2 * r_];
        v1 = isact ? XU[2 * r_ + 1] * eet1 : ac1[r_] * XU[2 * r_ + 1];
        if (T_ <= lm1[r_]) {
          *(unsigned*)&sVg[POUT][(4 * qd + r_) * STH + 32 * w + 2 * c] =
              pk_bf16(v0, v1);
          cloc[r_] = isact ? 0 : cloc[r_];
        }
      }
    }
  }
}

// ---------- Phase 1: recursions (blocks 0..31) + in-grid score -------------
// Blocks 0..15: fwd group bid;  16..31: bwd group bid-16.
// Blocks 32..543: gold-score.  Step body: fb8 (exp-hoist + x dbuf),
// norm cadence 4, STH=144, depth-2 MFMA chains (measured best, fb11).
__global__ __launch_bounds__(256, 1) void crf_fb13(
    const float* __restrict__ emit, const int* __restrict__ target,
    const void* __restrict__ maskp, const float* __restrict__ trans,
    const float* __restrict__ strans, const float* __restrict__ etrans,
    float* __restrict__ ws, int* __restrict__ lens, float* __restrict__ AF,
    int* __restrict__ CF, float* __restrict__ BU, int* __restrict__ CB) {
  __shared__ __align__(16) unsigned short sV[2][MW * STH];
  __shared__ __align__(16) int nrm[2][MW];
  __shared__ __align__(16) int sC[MW];
  __shared__ int slen[MW];
  __shared__ int smax_s;
  __shared__ float rf[4];

  const int bid = blockIdx.x;
  const int tid = threadIdx.x;
  const unsigned char* mk8 = (const unsigned char*)maskp;
  const int* mk32 = (const int*)maskp;
  const bool is_u8 = (mk8[1] != 0);

  if (bid >= 32) {
    // ---------------- gold score (one t per block) ----------------
    const int b = tid;
    const int t = bid - 32;
    int m = is_u8 ? (mk8[t * BB + b] != 0) : (mk32[t * BB + b] != 0);
    float v = 0.f;
    if (m) {
      int tg = target[t * BB + b];
      v = emit[((size_t)t * BB + b) * NN + tg];
      v += (t > 0) ? trans[target[(t - 1) * BB + b] * NN + tg] : strans[tg];
      int mn = (t + 1 < TT) ? (is_u8 ? (mk8[(t + 1) * BB + b] != 0)
                                     : (mk32[(t + 1) * BB + b] != 0))
                            : 0;
      if (!mn) {  // prefix-mask edge = last valid step
        v += etrans[tg];
        lens[b] = t + 1;
      }
    }
#pragma unroll
    for (int off = 32; off; off >>= 1) v += __shfl_down(v, off, 64);
    if ((b & 63) == 0) rf[b >> 6] = v;
    __syncthreads();
    if (b == 0) atomicAdd(&ws[1], rf[0] + rf[1] + rf[2] + rf[3]);
    return;
  }

  // ---------------- recursion block (one group) ----------------
  const bool bwd = (bid >= NWG);
  const int g = bwd ? bid - NWG : bid;
  const int bg = g * MW;
  const int w = tid >> 6, l = tid & 63, c = l & 15, qd = l >> 4;

  if (tid == 0) smax_s = 0;
  __syncthreads();
  // per-chain length via binary search on the prefix-true mask
  if (tid < MW) {
    const int b = bg + tid;
    int len = 1;
#pragma unroll
    for (int st = 256; st; st >>= 1) {
      int t2 = len + st;
      if (t2 <= TT) {
        bool mv = is_u8 ? (mk8[(size_t)(t2 - 1) * BB + b] != 0)
                        : (mk32[(size_t)(t2 - 1) * BB + b] != 0);
        if (mv) len = t2;
      }
    }
    slen[tid] = len;
    atomicMax(&smax_s, len);
  }

  // ---- E fragments (bwd: transposed orientation) ----
  short8_t eB[4][2];
#pragma unroll
  for (int kt = 0; kt < 4; ++kt)
#pragma unroll
    for (int u = 0; u < 2; ++u)
#pragma unroll
      for (int jj = 0; jj < 8; ++jj) {
        int kp = kt * 32 + qd * 8 + jj;
        int a_ = orig_j(kp);
        int b_ = 32 * w + 16 * u + c;
        float tv = bwd ? trans[b_ * NN + a_] : trans[a_ * NN + b_];
        eB[kt][u][jj] = (short)f2bf(__expf(tv));
      }
  const float eet0 = __expf(etrans[32 * w + c]);
  const float eet1 = __expf(etrans[32 * w + 16 + c]);

  // ---- init state ----
  {
    const int m = tid & 15;
    const int pbase = (tid >> 4) * 8;
    if (!bwd) {
      const int b = bg + m;
#pragma unroll
      for (int pp = 0; pp < 8; ++pp) {
        int p = pbase + pp;
        int j = orig_j(p);
        float v = __expf(strans[j] + emit[(size_t)b * NN + j]);
        sV[0][m * STH + p] = f2bf(v);
        if (p == 0)
          nrm[0][m] = ((int)((__float_as_uint(v) >> 23) & 0xFF)) - 120;
      }
    } else {
#pragma unroll
      for (int pp = 0; pp < 8; ++pp) {
        int p = pbase + pp;
        sV[0][m * STH + p] = 0x3F80;  // 1.0 bf16
        sV[1][m * STH + p] = 0x3F80;
        if (p == 0) { nrm[0][m] = 0; nrm[1][m] = 0; }
      }
    }
  }
  __syncthreads();
  const int smax = smax_s;
  int lm1[4];
#pragma unroll
  for (int r = 0; r < 4; ++r) lm1[r] = slen[4 * qd + r] - 1;

  int cloc[4] = {0, 0, 0, 0};
  int nb = 0;
  const bool nwriter = (w == 0 && c == 0);

  int off8[8];
#pragma unroll
  for (int r = 0; r < 4; ++r)
#pragma unroll
    for (int u = 0; u < 2; ++u)
      off8[r * 2 + u] = (bg + 4 * qd + r) * NN + 32 * w + 16 * u + c;

  int NIT, T0;
  if (!bwd) {
    const int LmaxF = (smax < 258) ? smax : 258;
    NIT = LmaxF - 1;  // steps T = 1..LmaxF-1 (T = T0 + it)
    T0 = 1;
  } else {
    NIT = (smax >= 259) ? smax - 258 : 0;  // steps T = smax-1..258 (T0 - it)
    T0 = smax - 1;
  }

  if (NIT > 0) {
    // prefetch init: ra = emit[T0], rb = emit[T0 +/- 1], x0 = exp(ra)
    float ra[8], rb[8], x0[8], x1[8];
    {
      const int a1 = bwd ? (T0 - 1 > 0 ? T0 - 1 : 0)
                         : (T0 + 1 < TT ? T0 + 1 : TT - 1);
#pragma unroll
      for (int i = 0; i < 8; ++i) {
        ra[i] = emit[(size_t)T0 * (BB * NN) + off8[i]];
        rb[i] = emit[(size_t)a1 * (BB * NN) + off8[i]];
      }
#pragma unroll
      for (int i = 0; i < 8; ++i) x0[i] = __expf(ra[i]);
    }
    // norm cadence 4 (exact 2^n bookkeeping; growth over 4 steps << f32 max)
    if (!bwd) {
      for (int itb = 0; itb < NIT; itb += 4) {
#pragma unroll
        for (int k = 0; k < 4; ++k) {
          const int it = itb + k;
          if (it >= NIT) break;  // NIT block-uniform: barrier-safe
          if ((k & 1) == 0)
            step_one<true>(T0 + it, k == 3, emit, sV, nrm, nb, cloc, lm1, off8,
                           ra, rb, x0, x1, eB, eet0, eet1, w, c, qd, nwriter);
          else
            step_one<true>(T0 + it, k == 3, emit, sV, nrm, nb, cloc, lm1, off8,
                           rb, ra, x1, x0, eB, eet0, eet1, w, c, qd, nwriter);
          BARRIER_LGKM();
        }
      }
    } else {
      for (int itb = 0; itb < NIT; itb += 4) {
#pragma unroll
        for (int k = 0; k < 4; ++k) {
          const int it = itb + k;
          if (it >= NIT) break;
          if ((k & 1) == 0)
            step_one<false>(T0 - it, k == 3, emit, sV, nrm, nb, cloc, lm1,
                            off8, ra, rb, x0, x1, eB, eet0, eet1, w, c, qd,
                            nwriter);
          else
            step_one<false>(T0 - it, k == 3, emit, sV, nrm, nb, cloc, lm1,
                            off8, rb, ra, x1, x0, eB, eet0, eet1, w, c, qd,
                            nwriter);
          BARRIER_LGKM();
        }
      }
    }
  }

  // ---- epilogue: dump per-chain state + pow2 counters to global ----
  if (nwriter)
    *(int4*)&sC[4 * qd] = make_int4(cloc[0], cloc[1], cloc[2], cloc[3]);
  __syncthreads();
  {
    const int m = tid >> 4, i16 = tid & 15;
    if (!bwd) {
      int nf = slen[m] - 1;
      if (nf > 257) nf = 257;
      const int pf = nf & 1;
#pragma unroll
      for (int pp = 0; pp < 8; ++pp) {
        int p = i16 * 8 + pp;
        AF[(size_t)(bg + m) * NN + p] = bf2f(sV[pf][m * STH + p]);
      }
      if (i16 == 0) CF[bg + m] = sC[m];
    } else {
      // active chains all end at t=258 -> parity 0; inactive: init (unused)
#pragma unroll
      for (int pp = 0; pp < 8; ++pp) {
        int p = i16 * 8 + pp;
        BU[(size_t)(bg + m) * NN + p] = bf2f(sV[0][m * STH + p]);
      }
      if (i16 == 0) CB[bg + m] = sC[m];
    }
  }
}

// ---------- Phase 2: combine.  logZ_b = ln2*(CF+CB) + ln(alpha_257 . E U_258)
// (len>=259) or ln2*CF + ln(alpha . exp(etrans)) (len<=258). ----------------
__global__ __launch_bounds__(256) void crf_comb(
    const float* __restrict__ trans, const float* __restrict__ etrans,
    const int* __restrict__ lens, const float* __restrict__ AF,
    const int* __restrict__ CF, const float* __restrict__ BU,
    const int* __restrict__ CB, float* __restrict__ ws,
    float* __restrict__ out) {
  __shared__ __align__(16) unsigned short sU[MW * STH];
  __shared__ float sRed[4][MW][2];
  __shared__ int slen[MW];
  const int tid = threadIdx.x;
  const int w = tid >> 6, l = tid & 63, c = l & 15, qd = l >> 4;
  const int g = blockIdx.x, bg = g * MW;

  if (tid < MW) slen[tid] = lens[bg + tid];
  {
    const int m = tid & 15, pbase = (tid >> 4) * 8;
#pragma unroll
    for (int pp = 0; pp < 8; ++pp) {
      int p = pbase + pp;
      sU[m * STH + p] = f2bf(BU[(size_t)(bg + m) * NN + p]);
    }
  }
  short8_t eB[4][2];
#pragma unroll
  for (int kt = 0; kt < 4; ++kt)
#pragma unroll
    for (int u = 0; u < 2; ++u)
#pragma unroll
      for (int jj = 0; jj < 8; ++jj) {
        int kp = kt * 32 + qd * 8 + jj;
        int a_ = orig_j(kp);
        int b_ = 32 * w + 16 * u + c;
        eB[kt][u][jj] = (short)f2bf(__expf(trans[b_ * NN + a_]));  // bwd orient
      }
  const float eet0 = __expf(etrans[32 * w + c]);
  const float eet1 = __expf(etrans[32 * w + 16 + c]);
  __syncthreads();

  const short8_t A0 = *(const short8_t*)&sU[c * STH + 0 + qd * 8];
  const short8_t A1 = *(const short8_t*)&sU[c * STH + 32 + qd * 8];
  const short8_t A2 = *(const short8_t*)&sU[c * STH + 64 + qd * 8];
  const short8_t A3 = *(const short8_t*)&sU[c * STH + 96 + qd * 8];
  f32x4 ac0 = {0.f, 0.f, 0.f, 0.f}, ac1 = {0.f, 0.f, 0.f, 0.f};
  ac0 = __builtin_amdgcn_mfma_f32_16x16x32_bf16(A0, eB[0][0], ac0, 0, 0, 0);
  ac1 = __builtin_amdgcn_mfma_f32_16x16x32_bf16(A0, eB[0][1], ac1, 0, 0, 0);
  ac0 = __builtin_amdgcn_mfma_f32_16x16x32_bf16(A1, eB[1][0], ac0, 0, 0, 0);
  ac1 = __builtin_amdgcn_mfma_f32_16x16x32_bf16(A1, eB[1][1], ac1, 0, 0, 0);
  ac0 = __builtin_amdgcn_mfma_f32_16x16x32_bf16(A2, eB[2][0], ac0, 0, 0, 0);
  ac1 = __builtin_amdgcn_mfma_f32_16x16x32_bf16(A2, eB[2][1], ac1, 0, 0, 0);
  ac0 = __builtin_amdgcn_mfma_f32_16x16x32_bf16(A3, eB[3][0], ac0, 0, 0, 0);
  ac1 = __builtin_amdgcn_mfma_f32_16x16x32_bf16(A3, eB[3][1], ac1, 0, 0, 0);

#pragma unroll
  for (int r_ = 0; r_ < 4; ++r_) {
    // alpha at cols i0 = 32w+c (p=32w+2c), i1 = 32w+16+c (p=32w+2c+1)
    float a0 = AF[(size_t)(bg + 4 * qd + r_) * NN + 32 * w + 2 * c];
    float a1 = AF[(size_t)(bg + 4 * qd + r_) * NN + 32 * w + 2 * c + 1];
    float dB = a0 * ac0[r_] + a1 * ac1[r_];
    float dA = a0 * eet0 + a1 * eet1;
#pragma unroll
    for (int mk = 1; mk < 16; mk <<= 1) {
      dB += __shfl_xor(dB, mk, 64);
      dA += __shfl_xor(dA, mk, 64);
    }
    if (c == 0) {
      sRed[w][4 * qd + r_][0] = dB;
      sRed[w][4 * qd + r_][1] = dA;
    }
  }
  __syncthreads();
  if (tid < MW) {
    float DB = sRed[0][tid][0] + sRed[1][tid][0] + sRed[2][tid][0] + sRed[3][tid][0];
    float DA = sRed[0][tid][1] + sRed[1][tid][1] + sRed[2][tid][1] + sRed[3][tid][1];
    const int len = slen[tid];
    const float LN2 = 0.6931471805599453f;
    float logZ;
    if (len >= 259)
      logZ = LN2 * (float)(CF[bg + tid] + CB[bg + tid]) + __logf(DB);
    else
      logZ = LN2 * (float)CF[bg + tid] + __logf(DA);
    atomicAdd(&ws[0], logZ);
  }
  __syncthreads();
  if (tid == 0) {
    __threadfence();
    unsigned old = atomicAdd((unsigned*)ws + 3, 1u);
    if (old == NWG - 1) {
      float zz = atomicAdd(&ws[0], 0.f);
      float ss = atomicAdd(&ws[1], 0.f);
      out[0] = (zz - ss) * (1.0f / (float)BB);
    }
  }
}

// ---------- Fallback (Round-5 fused kernel, verified) ----------------------
__global__ __launch_bounds__(256, 1) void crf_fused_fb(
    const float* __restrict__ emit, const int* __restrict__ target,
    const void* __restrict__ maskp, const float* __restrict__ trans,
    const float* __restrict__ strans, const float* __restrict__ etrans,
    float* __restrict__ ws, float* __restrict__ out) {
  __shared__ __align__(16) unsigned short sV[2][MW * STH];
  __shared__ __align__(16) int nrm[2][MW];
  __shared__ __align__(16) int sC[MW];
  __shared__ int slen[MW];
  __shared__ float sscore;
  __shared__ int smax;

  const int tid = threadIdx.x;
  const int w = tid >> 6;
  const int l = tid & 63;
  const int c = l & 15;
  const int qd = l >> 4;
  const int bg = blockIdx.x * MW;

  if (tid < MW) slen[tid] = 0;
  if (tid == 0) { sscore = 0.f; smax = 0; }
  __syncthreads();

  const unsigned char* mk8 = (const unsigned char*)maskp;
  const int* mk32 = (const int*)maskp;
  const bool is_u8 = (mk8[1] != 0);
  {
    const int mi = tid & 15;
    const int b = bg + mi;
    const int t0 = (tid >> 4) * 32;
    int cnt = 0;
    float sc = 0.f;
    for (int s = 0; s < 32; ++s) {
      int t = t0 + s;
      int m = is_u8 ? (mk8[t * BB + b] != 0) : (mk32[t * BB + b] != 0);
      if (m) {
        cnt++;
        int tg = target[t * BB + b];
        float v = emit[((size_t)t * BB + b) * NN + tg];
        v += (t > 0) ? trans[target[(t - 1) * BB + b] * NN + tg] : strans[tg];
        int mn = (t + 1 < TT) ? (is_u8 ? (mk8[(t + 1) * BB + b] != 0)
                                       : (mk32[(t + 1) * BB + b] != 0))
                              : 0;
        if (!mn) v += etrans[tg];
        sc += v;
      }
    }
    atomicAdd(&slen[mi], cnt);
    atomicAdd(&sscore, sc);
  }

  short8_t eB[4][2];
#pragma unroll
  for (int kt = 0; kt < 4; ++kt)
#pragma unroll
    for (int u = 0; u < 2; ++u)
#pragma unroll
      for (int jj = 0; jj < 8; ++jj) {
        int kp = kt * 32 + qd * 8 + jj;
        int i = orig_j(kp);
        int j = 32 * w + 16 * u + c;
        eB[kt][u][jj] = (short)f2bf(__expf(trans[i * NN + j]));
      }

  {
    const int m = tid & 15;
    const int b = bg + m;
    const int pbase = (tid >> 4) * 8;
#pragma unroll
    for (int pp = 0; pp < 8; ++pp) {
      int p = pbase + pp;
      int j = orig_j(p);
      float v = __expf(strans[j] + emit[(size_t)b * NN + j]);
      sV[0][m * STH + p] = f2bf(v);
      if (p == 0)
        nrm[0][m] = ((int)((__float_as_uint(v) >> 23) & 0xFF)) - 120;
    }
  }
  __syncthreads();

  if (tid < MW) atomicMax(&smax, slen[tid]);
  if (tid == 0) atomicAdd(&ws[1], sscore);
  __syncthreads();
  const int Lmax = smax;
  int lenr[4];
#pragma unroll
  for (int r = 0; r < 4; ++r) lenr[r] = slen[4 * qd + r];

  int off8[8];
#pragma unroll
  for (int r = 0; r < 4; ++r)
#pragma unroll
    for (int u = 0; u < 2; ++u)
      off8[r * 2 + u] = (bg + 4 * qd + r) * NN + 32 * w + 16 * u + c;

  float ra[8], rb[8], xv[8];
  {
#pragma unroll
    for (int i = 0; i < 8; ++i) ra[i] = emit[(size_t)1 * BB * NN + off8[i]];
#pragma unroll
    for (int i = 0; i < 8; ++i) rb[i] = emit[(size_t)2 * BB * NN + off8[i]];
#pragma unroll
    for (int i = 0; i < 8; ++i) xv[i] = __expf(ra[i]);
  }
  int cloc[4] = {0, 0, 0, 0};
  const bool nwriter = (w == 0 && c == 0);

#define CRF_STEP(T_, PIN, POUT, RL, RO)                                       \
  do {                                                                        \
    int tl = ((T_) + 2 < TT) ? (T_) + 2 : TT - 1;                             \
    const size_t gbase = (size_t)tl * (BB * NN);                              \
    _Pragma("unroll") for (int i_ = 0; i_ < 8; ++i_)                          \
        RL[i_] = emit[gbase + off8[i_]];                                      \
    const short8_t A0 = *(const short8_t*)&sV[PIN][c * STH + 0 + qd * 8];     \
    const short8_t A1 = *(const short8_t*)&sV[PIN][c * STH + 32 + qd * 8];    \
    const short8_t A2 = *(const short8_t*)&sV[PIN][c * STH + 64 + qd * 8];    \
    const short8_t A3 = *(const short8_t*)&sV[PIN][c * STH + 96 + qd * 8];    \
    const int4 nr = *(const int4*)&nrm[PIN][4 * qd];                          \
    f32x4 ac0 = {0.f, 0.f, 0.f, 0.f}, ac1 = {0.f, 0.f, 0.f, 0.f};             \
    ac0 = __builtin_amdgcn_mfma_f32_16x16x32_bf16(A0, eB[0][0], ac0, 0, 0, 0);\
    ac1 = __builtin_amdgcn_mfma_f32_16x16x32_bf16(A0, eB[0][1], ac1, 0, 0, 0);\
    ac0 = __builtin_amdgcn_mfma_f32_16x16x32_bf16(A1, eB[1][0], ac0, 0, 0, 0);\
    ac1 = __builtin_amdgcn_mfma_f32_16x16x32_bf16(A1, eB[1][1], ac1, 0, 0, 0);\
    ac0 = __builtin_amdgcn_mfma_f32_16x16x32_bf16(A2, eB[2][0], ac0, 0, 0, 0);\
    ac1 = __builtin_amdgcn_mfma_f32_16x16x32_bf16(A2, eB[2][1], ac1, 0, 0, 0);\
    ac0 = __builtin_amdgcn_mfma_f32_16x16x32_bf16(A3, eB[3][0], ac0, 0, 0, 0);\
    ac1 = __builtin_amdgcn_mfma_f32_16x16x32_bf16(A3, eB[3][1], ac1, 0, 0, 0);\
    const int nA[4] = {nr.x, nr.y, nr.z, nr.w};                               \
    int nnw[4];                                                               \
    _Pragma("unroll") for (int r_ = 0; r_ < 4; ++r_) {                        \
      float y0 = ac0[r_] * xv[2 * r_];                                        \
      float y1 = ac1[r_] * xv[2 * r_ + 1];                                    \
      float v0 = ldexpf(y0, -nA[r_]);                                         \
      float v1 = ldexpf(y1, -nA[r_]);                                         \
      if ((T_) < lenr[r_]) {                                                  \
        unsigned pk = (unsigned)f2bf(v0) | ((unsigned)f2bf(v1) << 16);        \
        *(unsigned*)&sV[POUT][(4 * qd + r_) * STH + 32 * w + 2 * c] = pk;     \
        cloc[r_] += nA[r_];                                                   \
      }                                                                       \
      nnw[r_] = ((int)((__float_as_uint(v0) >> 23) & 0xFF)) - 120;            \
    }                                                                         \
    if (nwriter)                                                              \
      *(int4*)&nrm[POUT][4 * qd] = make_int4(nnw[0], nnw[1], nnw[2], nnw[3]); \
    _Pragma("unroll") for (int i_ = 0; i_ < 8; ++i_)                          \
        xv[i_] = __expf(RO[i_]);                                              \
    __syncthreads();                                                          \
  } while (0)

  for (int t = 1; t < Lmax; t += 2) {
    CRF_STEP(t, 0, 1, ra, rb);
    if (t + 1 < Lmax) {
      CRF_STEP(t + 1, 1, 0, rb, ra);
    }
  }
#undef CRF_STEP

  if (nwriter) *(int4*)&sC[4 * qd] = make_int4(cloc[0], cloc[1], cloc[2], cloc[3]);
  __syncthreads();
  {
    const int m = tid >> 4, i16 = tid & 15;
    const int pb = (slen[m] - 1) & 1;
    float s = 0.f;
#pragma unroll
    for (int pp = 0; pp < 8; ++pp) {
      int p = i16 * 8 + pp;
      int j = orig_j(p);
      s += bf2f(sV[pb][m * STH + p]) * __expf(etrans[j]);
    }
    s += __shfl_xor(s, 1, 64);
    s += __shfl_xor(s, 2, 64);
    s += __shfl_xor(s, 4, 64);
    s += __shfl_xor(s, 8, 64);
    if (i16 == 0)
      atomicAdd(&ws[0], (float)sC[m] * 0.69314718f + __logf(s));
  }
  __syncthreads();
  if (tid == 0) {
    __threadfence();
    unsigned old = atomicAdd((unsigned*)ws + 3, 1u);
    if (old == NWG - 1) {
      float zz = atomicAdd(&ws[0], 0.f);
      float ss = atomicAdd(&ws[1], 0.f);
      out[0] = (zz - ss) * (1.0f / (float)BB);
    }
  }
}

extern "C" void kernel_launch(void* const* d_in, const int* in_sizes, int n_in,
                              void* d_out, int out_size, void* d_ws, size_t ws_size,
                              hipStream_t stream) {
  const float* emit = (const float*)d_in[0];
  const int* target = (const int*)d_in[1];
  const void* mask = (const void*)d_in[2];
  const float* trans = (const float*)d_in[3];
  const float* strans = (const float*)d_in[4];
  const float* etrans = (const float*)d_in[5];
  float* ws = (float*)d_ws;
  float* out = (float*)d_out;

  hipMemsetAsync(d_ws, 0, 16, stream);
  if (ws_size >= WS_NEED) {
    int* lens = (int*)((char*)d_ws + LENS_OFF);
    float* AF = (float*)((char*)d_ws + AF_OFF);
    int* CF = (int*)((char*)d_ws + CF_OFF);
    float* BU = (float*)((char*)d_ws + BU_OFF);
    int* CB = (int*)((char*)d_ws + CB_OFF);
    crf_fb13<<<GRID, 256, 0, stream>>>(emit, target, mask, trans, strans,
                                       etrans, ws, lens, AF, CF, BU, CB);
    crf_comb<<<NWG, 256, 0, stream>>>(trans, etrans, lens, AF, CF, BU, CB, ws,
                                      out);
  } else {
    crf_fused_fb<<<NWG, 256, 0, stream>>>(emit, target, mask, trans, strans,
                                          etrans, ws, out);
  }
}